// Round 2
// baseline (831.307 us; speedup 1.0000x reference)
//
#include <hip/hip_runtime.h>

#define Tq   4096
#define HIDN 2048
#define NHEAD 16
#define NKV  8
#define DH   128
#define QKVN 4096   // qkv rows-out width (Q 2048 | K 1024 | V 1024)

typedef unsigned short u16;
typedef unsigned int   u32;
typedef __attribute__((ext_vector_type(8))) __bf16 bf16x8;
typedef __attribute__((ext_vector_type(8))) u16    u16x8;
typedef __attribute__((ext_vector_type(4))) float  f32x4;

// global->LDS direct copy, 16B per lane, LDS dest = wave-uniform base + lane*16
#define GLD16(gp, lp) __builtin_amdgcn_global_load_lds( \
    (const __attribute__((address_space(1))) void*)(gp), \
    (__attribute__((address_space(3))) void*)(lp), 16, 0, 0)

__device__ __forceinline__ u16 f2bf(float f) {   // RNE fp32->bf16
  union { float f; u32 u; } v; v.f = f;
  return (u16)((v.u + 0x7fffu + ((v.u >> 16) & 1u)) >> 16);
}
__device__ __forceinline__ float bf2f(u32 bits) {
  union { u32 u; float f; } v; v.u = bits << 16;
  return v.f;
}

// ---------------- cast fp32 -> bf16, n multiple of 2048 ----------------
__global__ __launch_bounds__(256) void cast_bf16_kernel(const float* __restrict__ in,
                                                        u16* __restrict__ out, int n) {
  int i = (blockIdx.x * 256 + threadIdx.x) * 8;
  if (i >= n) return;
  f32x4 a = *(const f32x4*)(in + i);
  f32x4 b = *(const f32x4*)(in + i + 4);
  u16x8 o;
  #pragma unroll
  for (int j = 0; j < 4; ++j) { o[j] = f2bf(a[j]); o[4 + j] = f2bf(b[j]); }
  *(u16x8*)(out + i) = o;
}

// ---------------- GEMM: C[m][n] = sum_k A[m][k]*B[n][k], bf16 in ----------------
// m97 structure: 128x128 tile, BK=32, 4 waves (2x2), 4x4 16x16 frags per wave.
template<bool OUT_BF16>
__global__ __launch_bounds__(256) void gemm_bt_kernel(const u16* __restrict__ A,
                                                      const u16* __restrict__ B,
                                                      void* __restrict__ Cout,
                                                      int M, int N, int K) {
  __shared__ u16 As[128 * 32];
  __shared__ u16 Bs[128 * 32];
  const int tid = threadIdx.x;
  const int lane = tid & 63, wv = tid >> 6;
  const int wr = wv >> 1, wc = wv & 1;
  const int g = lane >> 4, c = lane & 15;
  const int nbn = N >> 7;
  const int bm = blockIdx.x / nbn, bn = blockIdx.x % nbn;
  const int m0 = bm << 7, n0 = bn << 7;

  // staging: chunk = tid + call*256 ; row = chunk>>2 ; koff = (chunk&3)*8
  const int srow = tid >> 2;
  const int sk8 = (tid & 3) * 8;
  const u16* gA0 = A + (size_t)(m0 + srow) * K + sk8;
  const u16* gA1 = gA0 + (size_t)64 * K;
  const u16* gB0 = B + (size_t)(n0 + srow) * K + sk8;
  const u16* gB1 = gB0 + (size_t)64 * K;
  u16* lA0 = As + (wv * 64) * 8;          // chunk base (16B chunks) for this wave
  u16* lA1 = As + (wv * 64 + 256) * 8;
  u16* lB0 = Bs + (wv * 64) * 8;
  u16* lB1 = Bs + (wv * 64 + 256) * 8;

  f32x4 acc[4][4] = {};

  for (int kt = 0; kt < K; kt += 32) {
    __syncthreads();                       // protect prev-iter LDS reads
    GLD16(gA0 + kt, lA0); GLD16(gA1 + kt, lA1);
    GLD16(gB0 + kt, lB0); GLD16(gB1 + kt, lB1);
    __syncthreads();                       // vmcnt(0) drain + barrier (compiler emits)
    bf16x8 af[4], bfr[4];
    #pragma unroll
    for (int mi = 0; mi < 4; ++mi)
      af[mi] = *(const bf16x8*)&As[(wr * 64 + mi * 16 + c) * 32 + g * 8];
    #pragma unroll
    for (int ni = 0; ni < 4; ++ni)
      bfr[ni] = *(const bf16x8*)&Bs[(wc * 64 + ni * 16 + c) * 32 + g * 8];
    #pragma unroll
    for (int mi = 0; mi < 4; ++mi)
      #pragma unroll
      for (int ni = 0; ni < 4; ++ni)
        acc[mi][ni] = __builtin_amdgcn_mfma_f32_16x16x32_bf16(af[mi], bfr[ni], acc[mi][ni], 0, 0, 0);
  }

  // epilogue: C/D layout col=lane&15, row=4*(lane>>4)+j (m89-verified)
  #pragma unroll
  for (int mi = 0; mi < 4; ++mi)
    #pragma unroll
    for (int ni = 0; ni < 4; ++ni) {
      const int row = m0 + wr * 64 + mi * 16 + 4 * g;
      const int col = n0 + wc * 64 + ni * 16 + c;
      #pragma unroll
      for (int j = 0; j < 4; ++j) {
        if (OUT_BF16) ((u16*)Cout)[(size_t)(row + j) * N + col] = f2bf(acc[mi][ni][j]);
        else          ((float*)Cout)[(size_t)(row + j) * N + col] = acc[mi][ni][j];
      }
    }
}

// ---------------- fused RMSNorm + RoPE, in place on q|k of qkv ----------------
// one wave per (t, head) over 24 heads (16 q + 8 k); lane holds d=2l,2l+1
__global__ __launch_bounds__(256) void normrope_kernel(u16* __restrict__ qkv,
                                                       const float* __restrict__ qw,
                                                       const float* __restrict__ kw) {
  const int tid = threadIdx.x, lane = tid & 63, wv = tid >> 6;
  const int wid = blockIdx.x * 4 + wv;     // 0 .. 98303
  const int t = wid / 24;
  const int hh = wid % 24;
  const int off = (hh < 16) ? hh * DH : 2048 + (hh - 16) * DH;
  const float* w = (hh < 16) ? qw : kw;
  u16* base = qkv + (size_t)t * QKVN + off;
  const int d0 = lane * 2;

  u32 raw = *(const u32*)(base + d0);
  float v0 = bf2f(raw & 0xffffu), v1 = bf2f(raw >> 16);
  float ss = v0 * v0 + v1 * v1;
  #pragma unroll
  for (int m = 1; m <= 32; m <<= 1) ss += __shfl_xor(ss, m);
  const float rn = rsqrtf(ss * (1.0f / 128.0f) + 1e-6f);
  float n0 = v0 * rn * w[d0];
  float n1 = v1 * rn * w[d0 + 1];
  // rotate-half pairing: (d, d+64) <-> lanes l, l+32
  float o0 = __shfl_xor(n0, 32);
  float o1 = __shfl_xor(n1, 32);
  const int j0 = (lane & 31) * 2;          // frequency index
  const float p = (float)t;                // positions == arange(T) by construction
  const float lf = 0.31143075889568947f;   // log2(1e6)/64
  float a0 = p * __builtin_exp2f(-lf * (float)j0);
  float a1 = p * __builtin_exp2f(-lf * (float)(j0 + 1));
  float c0 = cosf(a0), s0 = sinf(a0), c1 = cosf(a1), s1 = sinf(a1);
  float r0, r1;
  if (lane < 32) { r0 = n0 * c0 - o0 * s0; r1 = n1 * c1 - o1 * s1; }
  else           { r0 = n0 * c0 + o0 * s0; r1 = n1 * c1 + o1 * s1; }
  *(u32*)(base + d0) = (u32)f2bf(r0) | ((u32)f2bf(r1) << 16);
}

// ---------------- V transpose: qkv v-section [t][kvh][d] -> vt[kvh][d][t] ----------------
__global__ __launch_bounds__(256) void vtrans_kernel(const u16* __restrict__ qkv,
                                                     u16* __restrict__ vt) {
  __shared__ u16 tile[64][72];
  const int tid = threadIdx.x;
  const int b = blockIdx.x;                // 8 kvh * 64 t-tiles * 2 d-tiles
  const int kvh = b >> 7;
  const int r = b & 127;
  const int t0 = (r & 63) * 64;
  const int d0 = (r >> 6) * 64;
  #pragma unroll
  for (int i = 0; i < 2; ++i) {
    int cidx = tid + i * 256;
    int trow = cidx >> 3, dcol = (cidx & 7) * 8;
    u16x8 v = *(const u16x8*)&qkv[(size_t)(t0 + trow) * QKVN + 3072 + kvh * DH + d0 + dcol];
    *(u16x8*)&tile[trow][dcol] = v;
  }
  __syncthreads();
  #pragma unroll
  for (int i = 0; i < 2; ++i) {
    int cidx = tid + i * 256;
    int drow = cidx >> 3, tcol = (cidx & 7) * 8;
    u16x8 v;
    #pragma unroll
    for (int j = 0; j < 8; ++j) v[j] = tile[tcol + j][drow];
    *(u16x8*)&vt[(size_t)kvh * DH * Tq + (size_t)(d0 + drow) * Tq + t0 + tcol] = v;
  }
}

// ---------------- flash attention, causal, GQA ----------------
// Independent waves (no block barrier): wave owns 16 q rows of one head.
// Block packs {2 q-heads sharing a kv-head} x {2 adjacent strips} for cache locality.
__global__ __launch_bounds__(256) void attn_kernel(const u16* __restrict__ qkv,
                                                   const u16* __restrict__ vt,
                                                   u16* __restrict__ o) {
  __shared__ u16 Ps[4][16][72];            // per-wave P staging (pad 72 -> 2-way reads)
  const int tid = threadIdx.x, lane = tid & 63, wv = tid >> 6;
  const int g = lane >> 4, c = lane & 15;
  const int b = blockIdx.x;
  const int kvh = b & 7;
  const int sp = 127 - (b >> 3);           // longest strips dispatched first
  const int head = 2 * kvh + (wv & 1);
  const int strip = sp * 2 + (wv >> 1);
  const int q0 = strip * 16;
  const float c2 = 0.08838834764831845f * 1.4426950408889634f;  // scale*log2(e)

  bf16x8 qf[4];
  #pragma unroll
  for (int ks = 0; ks < 4; ++ks)
    qf[ks] = *(const bf16x8*)&qkv[(size_t)(q0 + c) * QKVN + head * DH + ks * 32 + g * 8];

  f32x4 oacc[8] = {};
  float mrow[4] = { -3e38f, -3e38f, -3e38f, -3e38f };
  float lrow[4] = { 0.f, 0.f, 0.f, 0.f };

  const u16* kbase = qkv + 2048 + kvh * DH;
  const u16* vbase = vt + (size_t)kvh * DH * Tq;

  const int nkvb = (q0 + 15) / 64 + 1;
  for (int kb = 0; kb < nkvb; ++kb) {
    const int kv0 = kb * 64;
    f32x4 s[4] = {};
    #pragma unroll
    for (int st = 0; st < 4; ++st)
      #pragma unroll
      for (int ks = 0; ks < 4; ++ks) {
        bf16x8 kf = *(const bf16x8*)&kbase[(size_t)(kv0 + st * 16 + c) * QKVN + ks * 32 + g * 8];
        s[st] = __builtin_amdgcn_mfma_f32_16x16x32_bf16(qf[ks], kf, s[st], 0, 0, 0);
      }
    if (kv0 + 63 > q0) {                   // diagonal block: causal mask (fixed gate)
      #pragma unroll
      for (int st = 0; st < 4; ++st) {
        const int kvc = kv0 + st * 16 + c;
        #pragma unroll
        for (int j = 0; j < 4; ++j)
          if (kvc > q0 + 4 * g + j) s[st][j] = -1e9f;
      }
    }
    // online softmax (rows live on the 16 lanes with same g)
    #pragma unroll
    for (int j = 0; j < 4; ++j) {
      float mx = fmaxf(fmaxf(s[0][j], s[1][j]), fmaxf(s[2][j], s[3][j]));
      mx = fmaxf(mx, __shfl_xor(mx, 1));
      mx = fmaxf(mx, __shfl_xor(mx, 2));
      mx = fmaxf(mx, __shfl_xor(mx, 4));
      mx = fmaxf(mx, __shfl_xor(mx, 8));
      const float mn = fmaxf(mrow[j], mx);
      const float alpha = __builtin_exp2f(c2 * (mrow[j] - mn));
      mrow[j] = mn;
      lrow[j] *= alpha;
      float ps = 0.f;
      #pragma unroll
      for (int st = 0; st < 4; ++st) {
        float pv = __builtin_exp2f(c2 * (s[st][j] - mn));
        s[st][j] = pv;
        ps += pv;
      }
      ps += __shfl_xor(ps, 1); ps += __shfl_xor(ps, 2);
      ps += __shfl_xor(ps, 4); ps += __shfl_xor(ps, 8);
      lrow[j] += ps;
      #pragma unroll
      for (int db = 0; db < 8; ++db) oacc[db][j] *= alpha;
    }
    // P -> per-wave LDS (C layout) then re-read as A-fragments
    #pragma unroll
    for (int st = 0; st < 4; ++st)
      #pragma unroll
      for (int j = 0; j < 4; ++j)
        Ps[wv][4 * g + j][st * 16 + c] = f2bf(s[st][j]);
    bf16x8 pa0 = *(const bf16x8*)&Ps[wv][c][g * 8];
    bf16x8 pa1 = *(const bf16x8*)&Ps[wv][c][32 + g * 8];
    #pragma unroll
    for (int db = 0; db < 8; ++db) {
      bf16x8 vf0 = *(const bf16x8*)&vbase[(size_t)(db * 16 + c) * Tq + kv0 + g * 8];
      oacc[db] = __builtin_amdgcn_mfma_f32_16x16x32_bf16(pa0, vf0, oacc[db], 0, 0, 0);
      bf16x8 vf1 = *(const bf16x8*)&vbase[(size_t)(db * 16 + c) * Tq + kv0 + 32 + g * 8];
      oacc[db] = __builtin_amdgcn_mfma_f32_16x16x32_bf16(pa1, vf1, oacc[db], 0, 0, 0);
    }
  }
  #pragma unroll
  for (int j = 0; j < 4; ++j) lrow[j] = 1.0f / lrow[j];
  #pragma unroll
  for (int db = 0; db < 8; ++db)
    #pragma unroll
    for (int j = 0; j < 4; ++j)
      o[(size_t)(q0 + 4 * g + j) * HIDN + head * DH + db * 16 + c] = f2bf(oacc[db][j] * lrow[j]);
}

// ---------------- launch ----------------
extern "C" void kernel_launch(void* const* d_in, const int* in_sizes, int n_in,
                              void* d_out, int out_size, void* d_ws, size_t ws_size,
                              hipStream_t stream) {
  const float* x    = (const float*)d_in[0];
  const float* qkvw = (const float*)d_in[1];
  const float* qnw  = (const float*)d_in[2];
  const float* knw  = (const float*)d_in[3];
  const float* ow   = (const float*)d_in[4];

  char* ws = (char*)d_ws;
  u16* xb   = (u16*)ws;                      // 16 MB, reused for ow_bf16 after GEMM1
  u16* wb   = (u16*)(ws + (16u << 20));      // 16 MB, reused for attn-out after GEMM1
  u16* qkvb = (u16*)(ws + (32u << 20));      // 32 MB
  u16* vtb  = (u16*)(ws + (64u << 20));      // 8 MB   (total 72 MB)
  u16* owb  = xb;
  u16* ob   = wb;

  cast_bf16_kernel<<<4096, 256, 0, stream>>>(x,    xb, Tq * HIDN);
  cast_bf16_kernel<<<4096, 256, 0, stream>>>(qkvw, wb, QKVN * HIDN);
  gemm_bt_kernel<true><<<1024, 256, 0, stream>>>(xb, wb, (void*)qkvb, Tq, QKVN, HIDN);
  normrope_kernel<<<24576, 256, 0, stream>>>(qkvb, qnw, knw);
  vtrans_kernel<<<1024, 256, 0, stream>>>(qkvb, vtb);
  cast_bf16_kernel<<<2048, 256, 0, stream>>>(ow, owb, HIDN * HIDN);
  attn_kernel<<<1024, 256, 0, stream>>>(qkvb, vtb, ob);
  gemm_bt_kernel<false><<<512, 256, 0, stream>>>(ob, owb, d_out, Tq, HIDN, HIDN);
}

// Round 3
// 519.269 us; speedup vs baseline: 1.6009x; 1.6009x over previous
//
#include <hip/hip_runtime.h>

#define Tq   4096
#define HIDN 2048
#define NHEAD 16
#define NKV  8
#define DH   128
#define QKVN 4096   // qkv rows-out width (Q 2048 | K 1024 | V 1024)

typedef unsigned short u16;
typedef unsigned int   u32;
typedef __attribute__((ext_vector_type(8))) __bf16 bf16x8;
typedef __attribute__((ext_vector_type(8))) u16    u16x8;
typedef __attribute__((ext_vector_type(4))) float  f32x4;

// global->LDS direct copy, 16B per lane, LDS dest = wave-uniform base + lane*16
#define GLD16(gp, lp) __builtin_amdgcn_global_load_lds( \
    (const __attribute__((address_space(1))) void*)(gp), \
    (__attribute__((address_space(3))) void*)(lp), 16, 0, 0)

__device__ __forceinline__ u16 f2bf(float f) {   // RNE fp32->bf16
  union { float f; u32 u; } v; v.f = f;
  return (u16)((v.u + 0x7fffu + ((v.u >> 16) & 1u)) >> 16);
}
__device__ __forceinline__ float bf2f(u32 bits) {
  union { u32 u; float f; } v; v.u = bits << 16;
  return v.f;
}

// ---------------- cast fp32 -> bf16, n multiple of 2048 ----------------
__global__ __launch_bounds__(256) void cast_bf16_kernel(const float* __restrict__ in,
                                                        u16* __restrict__ out, int n) {
  int i = (blockIdx.x * 256 + threadIdx.x) * 8;
  if (i >= n) return;
  f32x4 a = *(const f32x4*)(in + i);
  f32x4 b = *(const f32x4*)(in + i + 4);
  u16x8 o;
  #pragma unroll
  for (int j = 0; j < 4; ++j) { o[j] = f2bf(a[j]); o[4 + j] = f2bf(b[j]); }
  *(u16x8*)(out + i) = o;
}

// ---------------- GEMM: C[m][n] = sum_k A[m][k]*B[n][k], bf16 in ----------------
// m97 structure: 128x128 tile, BK=32, 4 waves (2x2), 4x4 16x16 frags per wave.
template<bool OUT_BF16>
__global__ __launch_bounds__(256) void gemm_bt_kernel(const u16* __restrict__ A,
                                                      const u16* __restrict__ B,
                                                      void* __restrict__ Cout,
                                                      int M, int N, int K) {
  __shared__ u16 As[128 * 32];
  __shared__ u16 Bs[128 * 32];
  const int tid = threadIdx.x;
  const int lane = tid & 63, wv = tid >> 6;
  const int wr = wv >> 1, wc = wv & 1;
  const int g = lane >> 4, c = lane & 15;
  const int nbn = N >> 7;
  const int bm = blockIdx.x / nbn, bn = blockIdx.x % nbn;
  const int m0 = bm << 7, n0 = bn << 7;

  const int srow = tid >> 2;
  const int sk8 = (tid & 3) * 8;
  const u16* gA0 = A + (size_t)(m0 + srow) * K + sk8;
  const u16* gA1 = gA0 + (size_t)64 * K;
  const u16* gB0 = B + (size_t)(n0 + srow) * K + sk8;
  const u16* gB1 = gB0 + (size_t)64 * K;
  u16* lA0 = As + (wv * 64) * 8;
  u16* lA1 = As + (wv * 64 + 256) * 8;
  u16* lB0 = Bs + (wv * 64) * 8;
  u16* lB1 = Bs + (wv * 64 + 256) * 8;

  f32x4 acc[4][4] = {};

  for (int kt = 0; kt < K; kt += 32) {
    __syncthreads();
    GLD16(gA0 + kt, lA0); GLD16(gA1 + kt, lA1);
    GLD16(gB0 + kt, lB0); GLD16(gB1 + kt, lB1);
    __syncthreads();
    bf16x8 af[4], bfr[4];
    #pragma unroll
    for (int mi = 0; mi < 4; ++mi)
      af[mi] = *(const bf16x8*)&As[(wr * 64 + mi * 16 + c) * 32 + g * 8];
    #pragma unroll
    for (int ni = 0; ni < 4; ++ni)
      bfr[ni] = *(const bf16x8*)&Bs[(wc * 64 + ni * 16 + c) * 32 + g * 8];
    #pragma unroll
    for (int mi = 0; mi < 4; ++mi)
      #pragma unroll
      for (int ni = 0; ni < 4; ++ni)
        acc[mi][ni] = __builtin_amdgcn_mfma_f32_16x16x32_bf16(af[mi], bfr[ni], acc[mi][ni], 0, 0, 0);
  }

  #pragma unroll
  for (int mi = 0; mi < 4; ++mi)
    #pragma unroll
    for (int ni = 0; ni < 4; ++ni) {
      const int row = m0 + wr * 64 + mi * 16 + 4 * g;
      const int col = n0 + wc * 64 + ni * 16 + c;
      #pragma unroll
      for (int j = 0; j < 4; ++j) {
        if (OUT_BF16) ((u16*)Cout)[(size_t)(row + j) * N + col] = f2bf(acc[mi][ni][j]);
        else          ((float*)Cout)[(size_t)(row + j) * N + col] = acc[mi][ni][j];
      }
    }
}

// ---------------- fused RMSNorm + RoPE, in place on q|k of qkv ----------------
__global__ __launch_bounds__(256) void normrope_kernel(u16* __restrict__ qkv,
                                                       const float* __restrict__ qw,
                                                       const float* __restrict__ kw) {
  const int tid = threadIdx.x, lane = tid & 63, wv = tid >> 6;
  const int wid = blockIdx.x * 4 + wv;
  const int t = wid / 24;
  const int hh = wid % 24;
  const int off = (hh < 16) ? hh * DH : 2048 + (hh - 16) * DH;
  const float* w = (hh < 16) ? qw : kw;
  u16* base = qkv + (size_t)t * QKVN + off;
  const int d0 = lane * 2;

  u32 raw = *(const u32*)(base + d0);
  float v0 = bf2f(raw & 0xffffu), v1 = bf2f(raw >> 16);
  float ss = v0 * v0 + v1 * v1;
  #pragma unroll
  for (int m = 1; m <= 32; m <<= 1) ss += __shfl_xor(ss, m);
  const float rn = rsqrtf(ss * (1.0f / 128.0f) + 1e-6f);
  float n0 = v0 * rn * w[d0];
  float n1 = v1 * rn * w[d0 + 1];
  float o0 = __shfl_xor(n0, 32);
  float o1 = __shfl_xor(n1, 32);
  const int j0 = (lane & 31) * 2;
  const float p = (float)t;                // positions == arange(T) by construction
  const float lf = 0.31143075889568947f;   // log2(1e6)/64
  float a0 = p * __builtin_exp2f(-lf * (float)j0);
  float a1 = p * __builtin_exp2f(-lf * (float)(j0 + 1));
  float c0 = cosf(a0), s0 = sinf(a0), c1 = cosf(a1), s1 = sinf(a1);
  float r0, r1;
  if (lane < 32) { r0 = n0 * c0 - o0 * s0; r1 = n1 * c1 - o1 * s1; }
  else           { r0 = n0 * c0 + o0 * s0; r1 = n1 * c1 + o1 * s1; }
  *(u32*)(base + d0) = (u32)f2bf(r0) | ((u32)f2bf(r1) << 16);
}

// ---------------- V transpose: qkv v-section [t][kvh][d] -> vt[kvh][d][t] ----------------
__global__ __launch_bounds__(256) void vtrans_kernel(const u16* __restrict__ qkv,
                                                     u16* __restrict__ vt) {
  __shared__ u16 tile[64][72];
  const int tid = threadIdx.x;
  const int b = blockIdx.x;
  const int kvh = b >> 7;
  const int r = b & 127;
  const int t0 = (r & 63) * 64;
  const int d0 = (r >> 6) * 64;
  #pragma unroll
  for (int i = 0; i < 2; ++i) {
    int cidx = tid + i * 256;
    int trow = cidx >> 3, dcol = (cidx & 7) * 8;
    u16x8 v = *(const u16x8*)&qkv[(size_t)(t0 + trow) * QKVN + 3072 + kvh * DH + d0 + dcol];
    *(u16x8*)&tile[trow][dcol] = v;
  }
  __syncthreads();
  #pragma unroll
  for (int i = 0; i < 2; ++i) {
    int cidx = tid + i * 256;
    int drow = cidx >> 3, tcol = (cidx & 7) * 8;
    u16x8 v;
    #pragma unroll
    for (int j = 0; j < 8; ++j) v[j] = tile[tcol + j][drow];
    *(u16x8*)&vt[(size_t)kvh * DH * Tq + (size_t)(d0 + drow) * Tq + t0 + tcol] = v;
  }
}

// ---------------- flash attention, causal, GQA — block-cooperative ----------------
// 512 threads = 8 waves. Block owns 128 q-rows of one head; wave wv owns 16 rows.
// K-tile [64][128] and V^T-tile [128][64] staged in LDS per kv-block, shared by all
// waves. XOR swizzle (16B-chunk ^= row&7) applied on the global SOURCE address
// (linear gload_lds dest) and the same XOR on ds_read side (rule #21).
__global__ __launch_bounds__(512) void attn2_kernel(const u16* __restrict__ qkv,
                                                    const u16* __restrict__ vt,
                                                    u16* __restrict__ o) {
  __shared__ u16 Ks[64 * 128];             // 16 KB, swizzled
  __shared__ u16 Vs[128 * 64];             // 16 KB, swizzled
  __shared__ u16 Ps[8][16][72];            // per-wave P staging (pad 72)
  const int tid = threadIdx.x, lane = tid & 63, wv = tid >> 6;
  const int g = lane >> 4, c = lane & 15;
  const int bid = blockIdx.x;
  // complementary pairing: bid and bid+256 get qt summing to 31 (CU load balance)
  const int qt = (bid < 256) ? (31 - (bid >> 4)) : ((bid - 256) >> 4);
  const int head = bid & 15;
  const int kvh = head >> 1;
  const int qblk0 = qt * 128;
  const int q0w = qblk0 + wv * 16;
  const float c2 = 0.08838834764831845f * 1.4426950408889634f;  // scale*log2(e)

  // per-lane staging source offsets (2 issues each for K and V)
  int koff[2], voff[2];
  #pragma unroll
  for (int j = 0; j < 2; ++j) {
    int i = j * 512 + wv * 64 + lane;
    int kr = i >> 4, kcc = i & 15;         // K tile: 64 rows x 16 chunks
    koff[j] = kr * QKVN + 2048 + kvh * DH + ((kcc ^ (kr & 7)) * 8);
    int vr = i >> 3, vcc = i & 7;          // V tile: 128 rows x 8 chunks
    voff[j] = vr * Tq + ((vcc ^ (vr & 7)) * 8);
  }
  const u16* vbase_g = vt + (size_t)kvh * DH * Tq;
  const int xk = c & 7;                    // read-side swizzle key

  // Q fragments (held in registers for the whole strip)
  bf16x8 qf[4];
  #pragma unroll
  for (int ks = 0; ks < 4; ++ks)
    qf[ks] = *(const bf16x8*)&qkv[(size_t)(q0w + c) * QKVN + head * DH + ks * 32 + g * 8];

  f32x4 oacc[8] = {};
  float mrow[4] = { -3e38f, -3e38f, -3e38f, -3e38f };
  float lrow[4] = { 0.f, 0.f, 0.f, 0.f };

  const int nkvb = qt * 2 + 2;
  for (int kb = 0; kb < nkvb; ++kb) {
    const int kv0 = kb * 64;
    __syncthreads();                       // everyone done reading prev tiles
    #pragma unroll
    for (int j = 0; j < 2; ++j) {
      GLD16(qkv + (size_t)kv0 * QKVN + koff[j], Ks + (j * 512 + wv * 64) * 8);
      GLD16(vbase_g + kv0 + voff[j],           Vs + (j * 512 + wv * 64) * 8);
    }
    __syncthreads();                       // tiles ready (vmcnt(0) drained)
    if (kv0 <= q0w + 15) {                 // wave-uniform: skip compute, keep barriers
      f32x4 s[4] = {};
      #pragma unroll
      for (int st = 0; st < 4; ++st)
        #pragma unroll
        for (int ks = 0; ks < 4; ++ks) {
          bf16x8 kf = *(const bf16x8*)&Ks[(st * 16 + c) * 128 + (((ks * 4 + g) ^ xk) * 8)];
          s[st] = __builtin_amdgcn_mfma_f32_16x16x32_bf16(qf[ks], kf, s[st], 0, 0, 0);
        }
      if (kv0 + 63 > q0w) {                // diagonal block: causal mask
        #pragma unroll
        for (int st = 0; st < 4; ++st) {
          const int kvc = kv0 + st * 16 + c;
          #pragma unroll
          for (int j = 0; j < 4; ++j)
            if (kvc > q0w + 4 * g + j) s[st][j] = -1e9f;
        }
      }
      // online softmax (rows live on the 16 lanes with same g)
      #pragma unroll
      for (int j = 0; j < 4; ++j) {
        float mx = fmaxf(fmaxf(s[0][j], s[1][j]), fmaxf(s[2][j], s[3][j]));
        mx = fmaxf(mx, __shfl_xor(mx, 1));
        mx = fmaxf(mx, __shfl_xor(mx, 2));
        mx = fmaxf(mx, __shfl_xor(mx, 4));
        mx = fmaxf(mx, __shfl_xor(mx, 8));
        const float mn = fmaxf(mrow[j], mx);
        const float alpha = __builtin_exp2f(c2 * (mrow[j] - mn));
        mrow[j] = mn;
        lrow[j] *= alpha;
        float ps = 0.f;
        #pragma unroll
        for (int st = 0; st < 4; ++st) {
          float pv = __builtin_exp2f(c2 * (s[st][j] - mn));
          s[st][j] = pv;
          ps += pv;
        }
        ps += __shfl_xor(ps, 1); ps += __shfl_xor(ps, 2);
        ps += __shfl_xor(ps, 4); ps += __shfl_xor(ps, 8);
        lrow[j] += ps;
        #pragma unroll
        for (int db = 0; db < 8; ++db) oacc[db][j] *= alpha;
      }
      // P -> per-wave LDS (C layout) then re-read as A-fragments
      #pragma unroll
      for (int st = 0; st < 4; ++st)
        #pragma unroll
        for (int j = 0; j < 4; ++j)
          Ps[wv][4 * g + j][st * 16 + c] = f2bf(s[st][j]);
      bf16x8 pa0 = *(const bf16x8*)&Ps[wv][c][g * 8];
      bf16x8 pa1 = *(const bf16x8*)&Ps[wv][c][32 + g * 8];
      #pragma unroll
      for (int db = 0; db < 8; ++db) {
        bf16x8 vf0 = *(const bf16x8*)&Vs[(db * 16 + c) * 64 + ((g ^ xk) * 8)];
        oacc[db] = __builtin_amdgcn_mfma_f32_16x16x32_bf16(pa0, vf0, oacc[db], 0, 0, 0);
        bf16x8 vf1 = *(const bf16x8*)&Vs[(db * 16 + c) * 64 + (((4 + g) ^ xk) * 8)];
        oacc[db] = __builtin_amdgcn_mfma_f32_16x16x32_bf16(pa1, vf1, oacc[db], 0, 0, 0);
      }
    }
  }
  #pragma unroll
  for (int j = 0; j < 4; ++j) lrow[j] = 1.0f / lrow[j];
  #pragma unroll
  for (int db = 0; db < 8; ++db)
    #pragma unroll
    for (int j = 0; j < 4; ++j)
      o[(size_t)(q0w + 4 * g + j) * HIDN + head * DH + db * 16 + c] = f2bf(oacc[db][j] * lrow[j]);
}

// ---------------- launch ----------------
extern "C" void kernel_launch(void* const* d_in, const int* in_sizes, int n_in,
                              void* d_out, int out_size, void* d_ws, size_t ws_size,
                              hipStream_t stream) {
  const float* x    = (const float*)d_in[0];
  const float* qkvw = (const float*)d_in[1];
  const float* qnw  = (const float*)d_in[2];
  const float* knw  = (const float*)d_in[3];
  const float* ow   = (const float*)d_in[4];

  char* ws = (char*)d_ws;
  u16* xb   = (u16*)ws;                      // 16 MB, reused for ow_bf16 after GEMM1
  u16* wb   = (u16*)(ws + (16u << 20));      // 16 MB, reused for attn-out after GEMM1
  u16* qkvb = (u16*)(ws + (32u << 20));      // 32 MB
  u16* vtb  = (u16*)(ws + (64u << 20));      // 8 MB   (total 72 MB)
  u16* owb  = xb;
  u16* ob   = wb;

  cast_bf16_kernel<<<4096, 256, 0, stream>>>(x,    xb, Tq * HIDN);
  cast_bf16_kernel<<<4096, 256, 0, stream>>>(qkvw, wb, QKVN * HIDN);
  gemm_bt_kernel<true><<<1024, 256, 0, stream>>>(xb, wb, (void*)qkvb, Tq, QKVN, HIDN);
  normrope_kernel<<<24576, 256, 0, stream>>>(qkvb, qnw, knw);
  vtrans_kernel<<<1024, 256, 0, stream>>>(qkvb, vtb);
  cast_bf16_kernel<<<2048, 256, 0, stream>>>(ow, owb, HIDN * HIDN);
  attn2_kernel<<<512, 512, 0, stream>>>(qkvb, vtb, ob);
  gemm_bt_kernel<false><<<512, 256, 0, stream>>>(ob, owb, d_out, Tq, HIDN, HIDN);
}

// Round 4
// 456.902 us; speedup vs baseline: 1.8194x; 1.1365x over previous
//
#include <hip/hip_runtime.h>

#define Tq   4096
#define HIDN 2048
#define NHEAD 16
#define NKV  8
#define DH   128
#define QKVN 4096   // qkv rows-out width (Q 2048 | K 1024 | V 1024)

typedef unsigned short u16;
typedef unsigned int   u32;
typedef __attribute__((ext_vector_type(8))) __bf16 bf16x8;
typedef __attribute__((ext_vector_type(8))) u16    u16x8;
typedef __attribute__((ext_vector_type(4))) float  f32x4;

// global->LDS direct copy, 16B per lane, LDS dest = wave-uniform base + lane*16
#define GLD16(gp, lp) __builtin_amdgcn_global_load_lds( \
    (const __attribute__((address_space(1))) void*)(gp), \
    (__attribute__((address_space(3))) void*)(lp), 16, 0, 0)

__device__ __forceinline__ u16 f2bf(float f) {   // RNE fp32->bf16
  union { float f; u32 u; } v; v.f = f;
  return (u16)((v.u + 0x7fffu + ((v.u >> 16) & 1u)) >> 16);
}
__device__ __forceinline__ float bf2f(u32 bits) {
  union { u32 u; float f; } v; v.u = bits << 16;
  return v.f;
}

// ---------------- cast fp32 -> bf16, n multiple of 2048 ----------------
__global__ __launch_bounds__(256) void cast_bf16_kernel(const float* __restrict__ in,
                                                        u16* __restrict__ out, int n) {
  int i = (blockIdx.x * 256 + threadIdx.x) * 8;
  if (i >= n) return;
  f32x4 a = *(const f32x4*)(in + i);
  f32x4 b = *(const f32x4*)(in + i + 4);
  u16x8 o;
  #pragma unroll
  for (int j = 0; j < 4; ++j) { o[j] = f2bf(a[j]); o[4 + j] = f2bf(b[j]); }
  *(u16x8*)(out + i) = o;
}

// ---------------- GEMM: C[m][n] = sum_k A[m][k]*B[n][k], bf16 in ----------------
template<bool OUT_BF16>
__global__ __launch_bounds__(256) void gemm_bt_kernel(const u16* __restrict__ A,
                                                      const u16* __restrict__ B,
                                                      void* __restrict__ Cout,
                                                      int M, int N, int K) {
  __shared__ u16 As[128 * 32];
  __shared__ u16 Bs[128 * 32];
  const int tid = threadIdx.x;
  const int lane = tid & 63, wv = tid >> 6;
  const int wr = wv >> 1, wc = wv & 1;
  const int g = lane >> 4, c = lane & 15;
  const int nbn = N >> 7;
  const int bm = blockIdx.x / nbn, bn = blockIdx.x % nbn;
  const int m0 = bm << 7, n0 = bn << 7;

  const int srow = tid >> 2;
  const int sk8 = (tid & 3) * 8;
  const u16* gA0 = A + (size_t)(m0 + srow) * K + sk8;
  const u16* gA1 = gA0 + (size_t)64 * K;
  const u16* gB0 = B + (size_t)(n0 + srow) * K + sk8;
  const u16* gB1 = gB0 + (size_t)64 * K;
  u16* lA0 = As + (wv * 64) * 8;
  u16* lA1 = As + (wv * 64 + 256) * 8;
  u16* lB0 = Bs + (wv * 64) * 8;
  u16* lB1 = Bs + (wv * 64 + 256) * 8;

  f32x4 acc[4][4] = {};

  for (int kt = 0; kt < K; kt += 32) {
    __syncthreads();
    GLD16(gA0 + kt, lA0); GLD16(gA1 + kt, lA1);
    GLD16(gB0 + kt, lB0); GLD16(gB1 + kt, lB1);
    __syncthreads();
    bf16x8 af[4], bfr[4];
    #pragma unroll
    for (int mi = 0; mi < 4; ++mi)
      af[mi] = *(const bf16x8*)&As[(wr * 64 + mi * 16 + c) * 32 + g * 8];
    #pragma unroll
    for (int ni = 0; ni < 4; ++ni)
      bfr[ni] = *(const bf16x8*)&Bs[(wc * 64 + ni * 16 + c) * 32 + g * 8];
    #pragma unroll
    for (int mi = 0; mi < 4; ++mi)
      #pragma unroll
      for (int ni = 0; ni < 4; ++ni)
        acc[mi][ni] = __builtin_amdgcn_mfma_f32_16x16x32_bf16(af[mi], bfr[ni], acc[mi][ni], 0, 0, 0);
  }

  #pragma unroll
  for (int mi = 0; mi < 4; ++mi)
    #pragma unroll
    for (int ni = 0; ni < 4; ++ni) {
      const int row = m0 + wr * 64 + mi * 16 + 4 * g;
      const int col = n0 + wc * 64 + ni * 16 + c;
      #pragma unroll
      for (int j = 0; j < 4; ++j) {
        if (OUT_BF16) ((u16*)Cout)[(size_t)(row + j) * N + col] = f2bf(acc[mi][ni][j]);
        else          ((float*)Cout)[(size_t)(row + j) * N + col] = acc[mi][ni][j];
      }
    }
}

// ---------------- fused RMSNorm + RoPE, in place on q|k of qkv ----------------
__global__ __launch_bounds__(256) void normrope_kernel(u16* __restrict__ qkv,
                                                       const float* __restrict__ qw,
                                                       const float* __restrict__ kw) {
  const int tid = threadIdx.x, lane = tid & 63, wv = tid >> 6;
  const int wid = blockIdx.x * 4 + wv;
  const int t = wid / 24;
  const int hh = wid % 24;
  const int off = (hh < 16) ? hh * DH : 2048 + (hh - 16) * DH;
  const float* w = (hh < 16) ? qw : kw;
  u16* base = qkv + (size_t)t * QKVN + off;
  const int d0 = lane * 2;

  u32 raw = *(const u32*)(base + d0);
  float v0 = bf2f(raw & 0xffffu), v1 = bf2f(raw >> 16);
  float ss = v0 * v0 + v1 * v1;
  #pragma unroll
  for (int m = 1; m <= 32; m <<= 1) ss += __shfl_xor(ss, m);
  const float rn = rsqrtf(ss * (1.0f / 128.0f) + 1e-6f);
  float n0 = v0 * rn * w[d0];
  float n1 = v1 * rn * w[d0 + 1];
  float o0 = __shfl_xor(n0, 32);
  float o1 = __shfl_xor(n1, 32);
  const int j0 = (lane & 31) * 2;
  const float p = (float)t;                // positions == arange(T) by construction
  const float lf = 0.31143075889568947f;   // log2(1e6)/64
  float a0 = p * __builtin_exp2f(-lf * (float)j0);
  float a1 = p * __builtin_exp2f(-lf * (float)(j0 + 1));
  float c0 = cosf(a0), s0 = sinf(a0), c1 = cosf(a1), s1 = sinf(a1);
  float r0, r1;
  if (lane < 32) { r0 = n0 * c0 - o0 * s0; r1 = n1 * c1 - o1 * s1; }
  else           { r0 = n0 * c0 + o0 * s0; r1 = n1 * c1 + o1 * s1; }
  *(u32*)(base + d0) = (u32)f2bf(r0) | ((u32)f2bf(r1) << 16);
}

// ---------------- V transpose: qkv v-section [t][kvh][d] -> vt[kvh][d][t] ----------------
__global__ __launch_bounds__(256) void vtrans_kernel(const u16* __restrict__ qkv,
                                                     u16* __restrict__ vt) {
  __shared__ u16 tile[64][72];
  const int tid = threadIdx.x;
  const int b = blockIdx.x;
  const int kvh = b >> 7;
  const int r = b & 127;
  const int t0 = (r & 63) * 64;
  const int d0 = (r >> 6) * 64;
  #pragma unroll
  for (int i = 0; i < 2; ++i) {
    int cidx = tid + i * 256;
    int trow = cidx >> 3, dcol = (cidx & 7) * 8;
    u16x8 v = *(const u16x8*)&qkv[(size_t)(t0 + trow) * QKVN + 3072 + kvh * DH + d0 + dcol];
    *(u16x8*)&tile[trow][dcol] = v;
  }
  __syncthreads();
  #pragma unroll
  for (int i = 0; i < 2; ++i) {
    int cidx = tid + i * 256;
    int drow = cidx >> 3, tcol = (cidx & 7) * 8;
    u16x8 v;
    #pragma unroll
    for (int j = 0; j < 8; ++j) v[j] = tile[tcol + j][drow];
    *(u16x8*)&vt[(size_t)kvh * DH * Tq + (size_t)(d0 + drow) * Tq + t0 + tcol] = v;
  }
}

// ---------------- flash attention, causal, GQA — balanced + reg-prefetch ----------------
// Grid 256: block = (head, pair p) handles q-tiles {p, 31-p} => 66 phases each (uniform).
// 8 waves x 16 q-rows. K/V prefetched to regs (T14), ds_write with dest XOR swizzle.
// Row-sums via MFMA ones-row (no lrow bookkeeping); defer-max (T13); cvt_pk P packing.
__global__ __launch_bounds__(512) void attn3_kernel(const u16* __restrict__ qkv,
                                                    const u16* __restrict__ vt,
                                                    u16* __restrict__ o) {
  __shared__ u16 Ks[64 * 128];             // 16 KB, dest-swizzled
  __shared__ u16 Vs[144 * 64];             // 18 KB: rows 0..127 V^T, 128=ones, 129..143=0
  __shared__ u16 Ps[8][16][72];            // per-wave P staging
  const int tid = threadIdx.x, lane = tid & 63, wv = tid >> 6;
  const int g = lane >> 4, c = lane & 15;
  const int bid = blockIdx.x;
  const int head = bid & 15;
  const int p = bid >> 4;                  // 0..15
  const int kvh = head >> 1;
  const float c2 = 0.08838834764831845f * 1.4426950408889634f;  // scale*log2(e)
  const float THR = 40.0f;                 // defer-max threshold (raw score units)
  const int xk = c & 7;                    // read-side swizzle key

  // ones/zero rows of Vs (rows 128..143), written once; row-constant => swizzle-proof
  for (int i = tid; i < 16 * 64; i += 512) Vs[128 * 64 + i] = (i < 64) ? 0x3F80 : 0;

  // staging geometry: lane handles chunks i0 = wv*64+lane, i1 = i0+512
  int kOff[2], kDst[2], vOff[2], vDst[2];
  #pragma unroll
  for (int j = 0; j < 2; ++j) {
    int i = j * 512 + wv * 64 + lane;
    int kr = i >> 4, kcc = i & 15;         // K: 64 rows x 16 chunks
    kOff[j] = kr * QKVN + 2048 + kvh * DH + kcc * 8;
    kDst[j] = kr * 128 + ((kcc ^ (kr & 7)) * 8);
    int vr = i >> 3, vcc = i & 7;          // V: 128 rows x 8 chunks
    vOff[j] = vr * Tq + vcc * 8;
    vDst[j] = vr * 64 + ((vcc ^ (vr & 7)) * 8);
  }
  const u16* vkv = vt + (size_t)kvh * DH * Tq;
  u16x8 kreg[2], vreg[2];

  #pragma unroll 1
  for (int seg = 0; seg < 2; ++seg) {
    const int qt = seg ? (31 - p) : p;
    const int q0w = qt * 128 + wv * 16;
    const int nkvb = qt * 2 + 2;

    bf16x8 qf[4];
    #pragma unroll
    for (int ks = 0; ks < 4; ++ks)
      qf[ks] = *(const bf16x8*)&qkv[(size_t)(q0w + c) * QKVN + head * DH + ks * 32 + g * 8];

    f32x4 oacc[9] = {};                    // [0..7]=O cols, [8]=row-sum (ones col)
    float mrow[4] = { -3e38f, -3e38f, -3e38f, -3e38f };

    // prologue prefetch of tile 0
    #pragma unroll
    for (int j = 0; j < 2; ++j) {
      kreg[j] = *(const u16x8*)(qkv + kOff[j]);
      vreg[j] = *(const u16x8*)(vkv + vOff[j]);
    }

    for (int kb = 0; kb < nkvb; ++kb) {
      const int kv0 = kb * 64;
      // commit prefetched regs to LDS
      #pragma unroll
      for (int j = 0; j < 2; ++j) {
        *(u16x8*)&Ks[kDst[j]] = kreg[j];
        *(u16x8*)&Vs[vDst[j]] = vreg[j];
      }
      __syncthreads();                     // tiles visible
      {                                    // prefetch next tile (clamped) into regs
        const int kvn = (kb + 1 < nkvb) ? (kv0 + 64) : kv0;
        #pragma unroll
        for (int j = 0; j < 2; ++j) {
          kreg[j] = *(const u16x8*)(qkv + (size_t)kvn * QKVN + kOff[j]);
          vreg[j] = *(const u16x8*)(vkv + kvn + vOff[j]);
        }
      }
      if (kv0 <= q0w + 15) {               // wave-uniform active gate
        f32x4 s[4] = {};
        #pragma unroll
        for (int st = 0; st < 4; ++st)
          #pragma unroll
          for (int ks = 0; ks < 4; ++ks) {
            bf16x8 kf = *(const bf16x8*)&Ks[(st * 16 + c) * 128 + (((ks * 4 + g) ^ xk) * 8)];
            s[st] = __builtin_amdgcn_mfma_f32_16x16x32_bf16(qf[ks], kf, s[st], 0, 0, 0);
          }
        if (kv0 + 63 > q0w) {              // diagonal: causal mask
          #pragma unroll
          for (int st = 0; st < 4; ++st) {
            const int kvc = kv0 + st * 16 + c;
            #pragma unroll
            for (int j = 0; j < 4; ++j)
              if (kvc > q0w + 4 * g + j) s[st][j] = -1e9f;
          }
        }
        // row max + defer-max check
        float mx[4];
        int need = 0;
        #pragma unroll
        for (int j = 0; j < 4; ++j) {
          float m3 = fmaxf(fmaxf(s[0][j], s[1][j]), fmaxf(s[2][j], s[3][j]));
          m3 = fmaxf(m3, __shfl_xor(m3, 1));
          m3 = fmaxf(m3, __shfl_xor(m3, 2));
          m3 = fmaxf(m3, __shfl_xor(m3, 4));
          m3 = fmaxf(m3, __shfl_xor(m3, 8));
          mx[j] = m3;
          need |= (m3 > mrow[j] + THR);
        }
        if (__any(need)) {                 // rescale path (rare after warmup)
          #pragma unroll
          for (int j = 0; j < 4; ++j) {
            const float mn = fmaxf(mrow[j], mx[j]);
            const float alpha = __builtin_exp2f(c2 * (mrow[j] - mn));
            mrow[j] = mn;
            #pragma unroll
            for (int db = 0; db < 9; ++db) oacc[db][j] *= alpha;
          }
        }
        // exponentials (stale-max safe: bounded by exp2(c2*THR)~=34)
        #pragma unroll
        for (int j = 0; j < 4; ++j) {
          const float cm = c2 * mrow[j];
          #pragma unroll
          for (int st = 0; st < 4; ++st)
            s[st][j] = __builtin_exp2f(c2 * s[st][j] - cm);
        }
        // pack P -> bf16 pairs, stage to LDS (C layout rows 4g+j)
        #pragma unroll
        for (int st = 0; st < 4; ++st) {
          u32 pk01, pk23;
          asm("v_cvt_pk_bf16_f32 %0, %1, %2" : "=v"(pk01) : "v"(s[st][0]), "v"(s[st][1]));
          asm("v_cvt_pk_bf16_f32 %0, %1, %2" : "=v"(pk23) : "v"(s[st][2]), "v"(s[st][3]));
          Ps[wv][4 * g + 0][st * 16 + c] = (u16)pk01;
          Ps[wv][4 * g + 1][st * 16 + c] = (u16)(pk01 >> 16);
          Ps[wv][4 * g + 2][st * 16 + c] = (u16)pk23;
          Ps[wv][4 * g + 3][st * 16 + c] = (u16)(pk23 >> 16);
        }
        bf16x8 pa0 = *(const bf16x8*)&Ps[wv][c][g * 8];
        bf16x8 pa1 = *(const bf16x8*)&Ps[wv][c][32 + g * 8];
        #pragma unroll
        for (int db = 0; db < 9; ++db) {
          bf16x8 vf0 = *(const bf16x8*)&Vs[(db * 16 + c) * 64 + ((g ^ xk) * 8)];
          oacc[db] = __builtin_amdgcn_mfma_f32_16x16x32_bf16(pa0, vf0, oacc[db], 0, 0, 0);
          bf16x8 vf1 = *(const bf16x8*)&Vs[(db * 16 + c) * 64 + (((4 + g) ^ xk) * 8)];
          oacc[db] = __builtin_amdgcn_mfma_f32_16x16x32_bf16(pa1, vf1, oacc[db], 0, 0, 0);
        }
      }
      __syncthreads();                     // all reads done before next phase's writes
    }

    // epilogue: lsum lives on c==0 lanes of oacc[8]; broadcast within 16-lane group
    #pragma unroll
    for (int j = 0; j < 4; ++j) {
      const float ls = __shfl(oacc[8][j], lane & 48);
      const float inv = 1.0f / ls;
      #pragma unroll
      for (int db = 0; db < 8; ++db)
        o[(size_t)(q0w + 4 * g + j) * HIDN + head * DH + db * 16 + c] = f2bf(oacc[db][j] * inv);
    }
  }
}

// ---------------- launch ----------------
extern "C" void kernel_launch(void* const* d_in, const int* in_sizes, int n_in,
                              void* d_out, int out_size, void* d_ws, size_t ws_size,
                              hipStream_t stream) {
  const float* x    = (const float*)d_in[0];
  const float* qkvw = (const float*)d_in[1];
  const float* qnw  = (const float*)d_in[2];
  const float* knw  = (const float*)d_in[3];
  const float* ow   = (const float*)d_in[4];

  char* ws = (char*)d_ws;
  u16* xb   = (u16*)ws;                      // 16 MB, reused for ow_bf16 after GEMM1
  u16* wb   = (u16*)(ws + (16u << 20));      // 16 MB, reused for attn-out after GEMM1
  u16* qkvb = (u16*)(ws + (32u << 20));      // 32 MB
  u16* vtb  = (u16*)(ws + (64u << 20));      // 8 MB   (total 72 MB)
  u16* owb  = xb;
  u16* ob   = wb;

  cast_bf16_kernel<<<4096, 256, 0, stream>>>(x,    xb, Tq * HIDN);
  cast_bf16_kernel<<<4096, 256, 0, stream>>>(qkvw, wb, QKVN * HIDN);
  gemm_bt_kernel<true><<<1024, 256, 0, stream>>>(xb, wb, (void*)qkvb, Tq, QKVN, HIDN);
  normrope_kernel<<<24576, 256, 0, stream>>>(qkvb, qnw, knw);
  vtrans_kernel<<<1024, 256, 0, stream>>>(qkvb, vtb);
  cast_bf16_kernel<<<2048, 256, 0, stream>>>(ow, owb, HIDN * HIDN);
  attn3_kernel<<<256, 512, 0, stream>>>(qkvb, vtb, ob);
  gemm_bt_kernel<false><<<512, 256, 0, stream>>>(ob, owb, d_out, Tq, HIDN, HIDN);
}